// Round 1
// baseline (285.071 us; speedup 1.0000x reference)
//
#include <hip/hip_runtime.h>
#include <math.h>

#define IM 128
#define BZ 32

typedef float v4f __attribute__((ext_vector_type(4)));

// Two-phase restructure.
//
// Phase A (dft_kernel): one block per (b,h). Row DFT
//   t[v] = sum_w x[w] e^{-2pi i v w/128}, scaled by 1/128.
// Stash tre -> out[b,v,0,h], tim -> out[b,v,1,h]  (rows 0..1 of the (b,v)
// tile double as a transpose buffer; phase B reads then overwrites them).
// blockIdx swizzle groups all h of a given b onto one XCD so the 16
// writers of each 64-B stash line share an L2 (per-XCD L2s not coherent).
//
// Phase B (emit_kernel): one block per (b,v). The output tile
// out[b,v,:,:] is a CONTIGUOUS 64 KB region:
//   out[h,w] = tre[h]*cos(A v w) - tim[h]*sin(A v w)
// = rank-2 outer product, 2 FMA/element, twiddles from an exact
// 128-entry LDS table (k = v*w mod 128). Wave stores are 1 KB
// sequential -- same access pattern as the 6 TB/s harness fill.
// v==128 blocks do the contiguous passthrough copy of input[:,1,:,:].

__global__ __launch_bounds__(256) void dft_kernel(const float* __restrict__ in,
                                                  float* __restrict__ out) {
    const int g   = blockIdx.x;                    // 0 .. 4095
    const int row = (g & 7) * (BZ * IM / 8) + (g >> 3);  // XCD-chunked
    const int b   = row >> 7;
    const int h   = row & (IM - 1);
    const int tid = threadIdx.x;                   // 0 .. 255

    const float A = 6.28318530717958647692f / (float)IM;   // 2*pi/128

    __shared__ float xr[IM];
    const float* xrow = in + (((size_t)b * 2 + 0) * IM + h) * IM;
    if (tid < IM) xr[tid] = xrow[tid];
    __syncthreads();

    // v = tid/2, each half sums 64 terms via phasor recurrence (proven path).
    const int v     = tid >> 1;
    const int part  = tid & 1;
    const int wbase = part << 6;                   // 0 or 64

    float pc, ps;
    { int k = (v * wbase) & (IM - 1); sincosf(A * (float)k, &ps, &pc); ps = -ps; }
    float rc, rs;
    sincosf(A * (float)v, &rs, &rc); rs = -rs;

    float sre = 0.0f, sim = 0.0f;
    #pragma unroll 8
    for (int i = 0; i < 64; ++i) {
        const float xv = xr[wbase + i];            // 2 addrs/wave: conflict-free
        sre = fmaf(xv, pc, sre);
        sim = fmaf(xv, ps, sim);
        const float npc = pc * rc - ps * rs;
        ps = fmaf(ps, rc, pc * rs);
        pc = npc;
    }
    sre += __shfl_xor(sre, 1);
    sim += __shfl_xor(sim, 1);

    if (part == 0) {
        float* tb = out + (size_t)(b * 129 + v) * (IM * IM);
        tb[h]      = sre * (1.0f / IM);            // stash tre at out[b,v,0,h]
        tb[IM + h] = sim * (1.0f / IM);            // stash tim at out[b,v,1,h]
    }
}

__global__ __launch_bounds__(256) void emit_kernel(const float* __restrict__ in,
                                                   float* __restrict__ out) {
    const int v   = blockIdx.x;                    // 0 .. 128
    const int b   = blockIdx.y;                    // 0 .. 31
    const int tid = threadIdx.x;                   // 0 .. 255
    float* base = out + (size_t)(b * 129 + v) * (IM * IM);

    if (v == IM) {
        // passthrough: out[b,128,:,:] = input[b,1,:,:]  (contiguous 64 KB copy)
        const v4f* src = (const v4f*)(in + ((size_t)b * 2 + 1) * IM * IM);
        v4f*       dst = (v4f*)base;
        #pragma unroll
        for (int it = 0; it < 16; ++it) dst[it * 256 + tid] = src[it * 256 + tid];
        return;
    }

    __shared__ float tr[IM], ti[IM], ct[IM], st[IM];
    const float A = 6.28318530717958647692f / (float)IM;
    if (tid < IM) {
        tr[tid] = base[tid];                       // read stash BEFORE overwrite
        ti[tid] = base[IM + tid];
        float s, c;
        sincosf(A * (float)tid, &s, &c);           // exact table cos/sin(2pi k/128)
        ct[tid] = c; st[tid] = s;
    }
    __syncthreads();

    const int w0 = (tid & 31) * 4;                 // 0,4,...,124
    const int hb = tid >> 5;                       // 0..7

    float cw[4], sw[4];
    #pragma unroll
    for (int j = 0; j < 4; ++j) {                  // fully unrolled: stays in regs
        const int k = (v * (w0 + j)) & (IM - 1);
        cw[j] = ct[k]; sw[j] = st[k];
    }

    #pragma unroll
    for (int it = 0; it < 16; ++it) {
        const int h  = it * 8 + hb;
        const float re = tr[h];                    // 2 addrs/wave: broadcast
        const float im = ti[h];
        v4f r;
        r.x = re * cw[0] - im * sw[0];
        r.y = re * cw[1] - im * sw[1];
        r.z = re * cw[2] - im * sw[2];
        r.w = re * cw[3] - im * sw[3];
        *(v4f*)(base + (size_t)h * IM + w0) = r;   // 1 KB/wave, sequential
    }
}

extern "C" void kernel_launch(void* const* d_in, const int* in_sizes, int n_in,
                              void* d_out, int out_size, void* d_ws, size_t ws_size,
                              hipStream_t stream) {
    const float* in = (const float*)d_in[0];   // (32, 2, 128, 128) fp32; mask unused
    float* out = (float*)d_out;                // (32, 129, 128, 128) fp32
    dft_kernel<<<dim3(BZ * IM), dim3(256), 0, stream>>>(in, out);
    emit_kernel<<<dim3(IM + 1, BZ), dim3(256), 0, stream>>>(in, out);
}

// Round 2
// 268.922 us; speedup vs baseline: 1.0600x; 1.0600x over previous
//
#include <hip/hip_runtime.h>
#include <math.h>

#define IM 128
#define BZ 32

typedef float v4f __attribute__((ext_vector_type(4)));

// Fused single-kernel design. One block per (b, c) where c = 16-wide v-chunk.
// Grid = 32 b x 8 c = 256 blocks (1 per CU), 256 threads, 65.5 KB LDS.
//
//   phase 1 (stage): x[b] (64 KB) -> LDS transposed xT[w][h], XOR-swizzled
//                    (h0 ^ ((w&31)<<2)) so stage ds_write_b128 and DFT
//                    ds_read_b128 are both bank-conflict-free.
//   phase 2 (DFT):   t[v,h] = sum_w x[h,w] e^{-2pi i v w/128} / 128.
//                    Thread = (q=tid>>5, h0=(tid&31)*4), v in {16c+q, 16c+q+8}:
//                    one b128 x-read feeds 2v x 4h = 8 sums (16 FMA), phasor
//                    recurrences in registers (no LDS twiddle traffic).
//                    tre/tim written into the dead first 16 KB of xs —
//                    the h-transpose stays in LDS, never touches HBM.
//   phase 3 (emit):  16 contiguous 64-KB tiles out[b, 16c+vt, :, :]:
//                    out[h,w] = tre[h]*cos(A v w) - tim[h]*sin(A v w),
//                    exact 128-entry LDS twiddle table, 1 KB/wave sequential
//                    stores (same access pattern as the 6.2 TB/s fill).
//   passthrough:     rows [16c,16c+16) of input[b,1] -> out[b,128] (8 KB/block,
//                    uniform across the grid).

__global__ __launch_bounds__(256) void kspace_fused(const float* __restrict__ in,
                                                    float* __restrict__ out) {
    const int blk = blockIdx.x;        // 0..255
    const int b   = blk >> 3;          // 0..31
    const int c   = blk & 7;           // v-chunk: v in [16c, 16c+16)
    const int tid = threadIdx.x;       // 0..255

    const float A = 6.28318530717958647692f / (float)IM;   // 2*pi/128

    __shared__ float xs[IM * IM];      // 64 KB: xT during DFT, then tre/tim
    __shared__ float ct[IM], st[IM];   // exact emit twiddles

    // ---- phase 1: stage xT[w][h] (swizzled) + twiddle table ----
    const float* xg = in + (size_t)b * 2 * IM * IM;
    {
        const int w  = tid & 127;
        const int hq = tid >> 7;                       // 0..1
        if (tid < IM) {
            float s, cc; sincosf(A * (float)tid, &s, &cc);
            ct[tid] = cc; st[tid] = s;
        }
        #pragma unroll
        for (int p = 0; p < 16; ++p) {
            const int h0 = p * 8 + hq * 4;             // coalesced b32 loads
            v4f t;
            t.x = xg[(h0 + 0) * IM + w];
            t.y = xg[(h0 + 1) * IM + w];
            t.z = xg[(h0 + 2) * IM + w];
            t.w = xg[(h0 + 3) * IM + w];
            *(v4f*)(xs + w * IM + (h0 ^ ((w & 31) << 2))) = t;   // conflict-free
        }
    }
    __syncthreads();

    // ---- phase 2: DFT ----
    {
        const int q  = tid >> 5;                       // 0..7
        const int h0 = (tid & 31) * 4;                 // 0,4,...,124
        const int va = c * 16 + q;
        const int vb = va + 8;

        float rc0, rs0, rc1, rs1;
        sincosf(A * (float)va, &rs0, &rc0); rs0 = -rs0;   // step e^{-iAv}
        sincosf(A * (float)vb, &rs1, &rc1); rs1 = -rs1;
        float pc0 = 1.0f, ps0 = 0.0f, pc1 = 1.0f, ps1 = 0.0f;

        float sre0[4] = {0,0,0,0}, sim0[4] = {0,0,0,0};
        float sre1[4] = {0,0,0,0}, sim1[4] = {0,0,0,0};

        #pragma unroll 4
        for (int w = 0; w < IM; ++w) {
            const v4f xv = *(const v4f*)(xs + w * IM + (h0 ^ ((w & 31) << 2)));
            sre0[0] = fmaf(xv.x, pc0, sre0[0]); sim0[0] = fmaf(xv.x, ps0, sim0[0]);
            sre0[1] = fmaf(xv.y, pc0, sre0[1]); sim0[1] = fmaf(xv.y, ps0, sim0[1]);
            sre0[2] = fmaf(xv.z, pc0, sre0[2]); sim0[2] = fmaf(xv.z, ps0, sim0[2]);
            sre0[3] = fmaf(xv.w, pc0, sre0[3]); sim0[3] = fmaf(xv.w, ps0, sim0[3]);
            sre1[0] = fmaf(xv.x, pc1, sre1[0]); sim1[0] = fmaf(xv.x, ps1, sim1[0]);
            sre1[1] = fmaf(xv.y, pc1, sre1[1]); sim1[1] = fmaf(xv.y, ps1, sim1[1]);
            sre1[2] = fmaf(xv.z, pc1, sre1[2]); sim1[2] = fmaf(xv.z, ps1, sim1[2]);
            sre1[3] = fmaf(xv.w, pc1, sre1[3]); sim1[3] = fmaf(xv.w, ps1, sim1[3]);
            const float n0 = pc0 * rc0 - ps0 * rs0;
            ps0 = fmaf(ps0, rc0, pc0 * rs0); pc0 = n0;
            const float n1 = pc1 * rc1 - ps1 * rs1;
            ps1 = fmaf(ps1, rc1, pc1 * rs1); pc1 = n1;
        }
        __syncthreads();                               // all xT reads done

        const float inv = 1.0f / (float)IM;
        v4f tr0, ti0, tr1, ti1;
        tr0.x = sre0[0]*inv; tr0.y = sre0[1]*inv; tr0.z = sre0[2]*inv; tr0.w = sre0[3]*inv;
        ti0.x = sim0[0]*inv; ti0.y = sim0[1]*inv; ti0.z = sim0[2]*inv; ti0.w = sim0[3]*inv;
        tr1.x = sre1[0]*inv; tr1.y = sre1[1]*inv; tr1.z = sre1[2]*inv; tr1.w = sre1[3]*inv;
        ti1.x = sim1[0]*inv; ti1.y = sim1[1]*inv; ti1.z = sim1[2]*inv; ti1.w = sim1[3]*inv;
        *(v4f*)(xs +        q      * IM + h0) = tr0;   // tre[vt][h]: xs[0..2047]
        *(v4f*)(xs + 2048 + q      * IM + h0) = ti0;   // tim[vt][h]: xs[2048..4095]
        *(v4f*)(xs +        (q+8)  * IM + h0) = tr1;
        *(v4f*)(xs + 2048 + (q+8)  * IM + h0) = ti1;
    }
    __syncthreads();

    // ---- phase 3: emit 16 contiguous 64-KB tiles ----
    const int w0   = (tid & 31) * 4;                   // 0,4,...,124
    const int hsub = tid >> 5;                         // 0..7
    float* tiles = out + ((size_t)b * 129 + c * 16) * (IM * IM);

    for (int vt = 0; vt < 16; ++vt) {
        const int v = c * 16 + vt;
        int k = (v * w0) & (IM - 1);                   // exact: k = v*w mod 128
        const float cw0 = ct[k], sw0 = st[k]; k = (k + v) & (IM - 1);
        const float cw1 = ct[k], sw1 = st[k]; k = (k + v) & (IM - 1);
        const float cw2 = ct[k], sw2 = st[k]; k = (k + v) & (IM - 1);
        const float cw3 = ct[k], sw3 = st[k];
        float* tb = tiles + (size_t)vt * (IM * IM);
        const float* trw = xs + vt * IM;
        const float* tiw = xs + 2048 + vt * IM;
        #pragma unroll
        for (int i = 0; i < 16; ++i) {
            const int h = i * 8 + hsub;
            const float re = trw[h];                   // 2-addr broadcast
            const float im = tiw[h];
            v4f r;
            r.x = re * cw0 - im * sw0;
            r.y = re * cw1 - im * sw1;
            r.z = re * cw2 - im * sw2;
            r.w = re * cw3 - im * sw3;
            *(v4f*)(tb + h * IM + w0) = r;             // 1 KB/wave, sequential
        }
    }

    // ---- passthrough: rows [16c, 16c+16) of input[b,1] -> out[b,128] ----
    {
        const v4f* src = (const v4f*)(in + ((size_t)b * 2 + 1) * IM * IM + c * 16 * IM);
        v4f*       dst = (v4f*)(out + ((size_t)b * 129 + 128) * IM * IM + c * 16 * IM);
        dst[tid]       = src[tid];                     // 512 v4f total
        dst[256 + tid] = src[256 + tid];
    }
}

extern "C" void kernel_launch(void* const* d_in, const int* in_sizes, int n_in,
                              void* d_out, int out_size, void* d_ws, size_t ws_size,
                              hipStream_t stream) {
    const float* in = (const float*)d_in[0];   // (32, 2, 128, 128) fp32; mask unused
    float* out = (float*)d_out;                // (32, 129, 128, 128) fp32
    kspace_fused<<<dim3(BZ * 8), dim3(256), 0, stream>>>(in, out);
}